// Round 1
// baseline (219.494 us; speedup 1.0000x reference)
//
#include <hip/hip_runtime.h>
#include <hip/hip_bf16.h>

// RefinementLayer2: B=2,S=384,C=4,H=128,D=768
// ws layout (floats): tanh_hp[393216] | h_a[393216] | tanh_ha[393216] |
//   tanh_ref[393216] | tprd_s[393216] | tref_s[98304] | targ_s(bf16)[393216]
// total ~9.04 MB of d_ws.

#define C2 2.885390081777927f  // 2/ln(2): exp2(C2*x) = e^(2x)

typedef __attribute__((ext_vector_type(8))) __bf16 bf16x8;
typedef __attribute__((ext_vector_type(8))) unsigned short ushort8;
typedef __attribute__((ext_vector_type(4))) float float4v;

__device__ __forceinline__ unsigned short f2bf(float f) {
  unsigned int u = __float_as_uint(f);
  u += 0x7fffu + ((u >> 16) & 1u);   // round-nearest-even
  return (unsigned short)(u >> 16);
}

__device__ __forceinline__ float fast_tanh(float x) {
  // tanh(x) = 1 - 2/(1+e^(2x)); e=inf -> rcp -> 0 -> +1; e=0 -> 1-2 = -1. Safe.
  float e = __builtin_amdgcn_exp2f(C2 * x);
  return 1.0f - 2.0f * __builtin_amdgcn_rcpf(1.0f + e);
}

// ---------------------------------------------------------------------------
// Generic fp32-in bf16-MFMA GEMM.  C = A(MxK) * B(KxN) + bias.
// 64x64 block tile, BK=32, 256 threads (4 waves, each wave 32x32 = 2x2 MFMA).
// Batched via blockIdx.z: off = (z>>2)*Sb + (z&3)*Sc for A/B/C.
// Outputs (any may be null): outF = scale*(C+bias) fp32; outB = bf16 of same;
//                            outT = tanh(C+bias) fp32.
// Requires: M%64==0, N%64==0, K%32==0, lda/ldb multiples of 4, 16B-aligned ptrs.
// ---------------------------------------------------------------------------
__global__ __launch_bounds__(256) void gemm_bf16(
    const float* __restrict__ A, int lda, long aSb, long aSc,
    const float* __restrict__ B, int ldb, long bSb, long bSc,
    const float* __restrict__ bias,
    int M, int N, int K,
    float* __restrict__ outF, unsigned short* __restrict__ outB,
    float* __restrict__ outT, int ldc, long cSb, long cSc, float scale)
{
  __shared__ unsigned short Alds[64 * 40];  // [m][k], pad 32->40 to break banks
  __shared__ unsigned short Blds[64 * 40];  // [n][k] (transposed), padded

  const int tid = threadIdx.x;
  const int z = blockIdx.z;
  const long aoff = (long)(z >> 2) * aSb + (long)(z & 3) * aSc;
  const long boff = (long)(z >> 2) * bSb + (long)(z & 3) * bSc;
  const long coff = (long)(z >> 2) * cSb + (long)(z & 3) * cSc;
  const int bn0 = blockIdx.x * 64;
  const int bm0 = blockIdx.y * 64;
  const int wid = tid >> 6, lane = tid & 63;
  const int wm0 = (wid >> 1) * 32, wn0 = (wid & 1) * 32;
  const int col16 = lane & 15, quad = lane >> 4;

  float4v acc[2][2];
#pragma unroll
  for (int i = 0; i < 2; ++i)
#pragma unroll
    for (int j = 0; j < 2; ++j) acc[i][j] = (float4v)(0.f);

  // staging maps: A: thread -> (row=tid>>2, col8=(tid&3)*8); B: (k=tid>>3, n8=(tid&7)*8)
  const int ar = tid >> 2, ac = (tid & 3) * 8;
  const int bk = tid >> 3, bn = (tid & 7) * 8;

  for (int k0 = 0; k0 < K; k0 += 32) {
    __syncthreads();
    {  // stage A tile (64x32) fp32 -> bf16
      const float4* s4 = (const float4*)(A + aoff + (size_t)(bm0 + ar) * lda + k0 + ac);
      float4 v0 = s4[0], v1 = s4[1];
      ushort8 o;
      o[0] = f2bf(v0.x); o[1] = f2bf(v0.y); o[2] = f2bf(v0.z); o[3] = f2bf(v0.w);
      o[4] = f2bf(v1.x); o[5] = f2bf(v1.y); o[6] = f2bf(v1.z); o[7] = f2bf(v1.w);
      *(ushort8*)&Alds[ar * 40 + ac] = o;
    }
    {  // stage B tile (32x64) fp32 -> bf16, transposed into [n][k]
      const float4* s4 = (const float4*)(B + boff + (size_t)(k0 + bk) * ldb + bn0 + bn);
      float4 v0 = s4[0], v1 = s4[1];
      float vv[8] = {v0.x, v0.y, v0.z, v0.w, v1.x, v1.y, v1.z, v1.w};
#pragma unroll
      for (int j = 0; j < 8; ++j) Blds[(bn + j) * 40 + bk] = f2bf(vv[j]);
    }
    __syncthreads();

    bf16x8 afrag[2], bfrag[2];
#pragma unroll
    for (int i = 0; i < 2; ++i)
      afrag[i] = __builtin_bit_cast(bf16x8,
          *(const ushort8*)&Alds[(wm0 + i * 16 + col16) * 40 + quad * 8]);
#pragma unroll
    for (int j = 0; j < 2; ++j)
      bfrag[j] = __builtin_bit_cast(bf16x8,
          *(const ushort8*)&Blds[(wn0 + j * 16 + col16) * 40 + quad * 8]);
#pragma unroll
    for (int i = 0; i < 2; ++i)
#pragma unroll
      for (int j = 0; j < 2; ++j)
        acc[i][j] = __builtin_amdgcn_mfma_f32_16x16x32_bf16(
            afrag[i], bfrag[j], acc[i][j], 0, 0, 0);
  }

  // epilogue: C/D layout col=lane&15, row=quad*4+reg
#pragma unroll
  for (int j = 0; j < 2; ++j) {
    const int gcol = bn0 + wn0 + j * 16 + col16;
    const float bv = bias ? bias[gcol] : 0.f;
#pragma unroll
    for (int i = 0; i < 2; ++i) {
#pragma unroll
      for (int r = 0; r < 4; ++r) {
        const int grow = bm0 + wm0 + i * 16 + quad * 4 + r;
        const float x = acc[i][j][r] + bv;
        const size_t cidx = (size_t)grow * ldc + gcol + coff;
        if (outF) outF[cidx] = scale * x;
        if (outB) outB[cidx] = f2bf(scale * x);
        if (outT) outT[cidx] = fast_tanh(x);
      }
    }
  }
}

// ---------------------------------------------------------------------------
// Phase 2: out[b,p,c,a] = sum_k w[k] * tanh(t_prd[b,p,c,k] + t_arg[b,a,c,k]
//                                          + t_ref[b,p,k] + b_mid[k])
// Inputs pre-scaled by C2 (tprd,targ,tref); b_mid scaled here.
// tanh via 1 - 2*rcp(1+exp2(t)); out = Sum(w) + Sum(-2*w_k * r_k).
// Block: 128 threads (thread <-> a-local), tiles: a=128, p=8, per (b,c).
// LDS: G tile 128x64 uints bf16x2 (stride 65 -> conflict-free), F 8x128 f32, W.
// ---------------------------------------------------------------------------
__global__ __launch_bounds__(128) void phase2(
    const float* __restrict__ tprd, const unsigned short* __restrict__ targ,
    const float* __restrict__ tref, const float* __restrict__ bmid,
    const float* __restrict__ wout, float* __restrict__ out)
{
  __shared__ unsigned int Gs[128 * 65];
  __shared__ float Fs[8 * 128];
  __shared__ float Ws[128];

  const int tid = threadIdx.x;
  const int pt = blockIdx.x, at = blockIdx.y;
  const int b = blockIdx.z >> 2, c = blockIdx.z & 3;
  const int p0 = pt * 8, a0 = at * 128;

  if (tid < 32) {  // Ws = -2 * w_out
    float4 w = ((const float4*)wout)[tid];
    Ws[tid * 4 + 0] = -2.f * w.x; Ws[tid * 4 + 1] = -2.f * w.y;
    Ws[tid * 4 + 2] = -2.f * w.z; Ws[tid * 4 + 3] = -2.f * w.w;
  }
  {  // stage G: 128 rows (a) x 64 uints (k-pairs)
    const unsigned int* gsrc = (const unsigned int*)targ;
#pragma unroll 4
    for (int it = 0; it < 64; ++it) {
      int idx = it * 128 + tid;
      int r = idx >> 6, col2 = idx & 63;
      Gs[r * 65 + col2] = gsrc[(size_t)((b * 384 + a0 + r) * 4 + c) * 64 + col2];
    }
  }
  {  // stage F[p][k] = tprd + tref + C2*bmid   (all already *C2 except bmid)
#pragma unroll
    for (int it = 0; it < 8; ++it) {
      int idx = it * 128 + tid;
      int p = idx >> 7, k = idx & 127;
      int row = b * 384 + p0 + p;
      Fs[idx] = tprd[(size_t)(row * 4 + c) * 128 + k] +
                tref[(size_t)row * 128 + k] + C2 * bmid[k];
    }
  }
  float sw = 0.f;  // Sum(w_out) via uniform (scalar) global loads
  for (int k = 0; k < 32; ++k) {
    float4 w = ((const float4*)wout)[k];
    sw += w.x + w.y + w.z + w.w;
  }
  __syncthreads();

  float acc[8];
#pragma unroll
  for (int p = 0; p < 8; ++p) acc[p] = 0.f;

  const unsigned int* g = &Gs[tid * 65];
  const float2* Wp2 = (const float2*)Ws;
  for (int kk = 0; kk < 64; ++kk) {
    unsigned int gp = g[kk];
    float g0 = __uint_as_float(gp << 16);
    float g1 = __uint_as_float(gp & 0xffff0000u);
    float2 w = Wp2[kk];
#pragma unroll
    for (int p = 0; p < 8; ++p) {
      float2 f = *(const float2*)&Fs[p * 128 + kk * 2];
      float r0 = __builtin_amdgcn_rcpf(1.f + __builtin_amdgcn_exp2f(f.x + g0));
      float r1 = __builtin_amdgcn_rcpf(1.f + __builtin_amdgcn_exp2f(f.y + g1));
      acc[p] = fmaf(w.x, r0, fmaf(w.y, r1, acc[p]));
    }
  }

#pragma unroll
  for (int p = 0; p < 8; ++p)
    out[(size_t)((b * 384 + p0 + p) * 4 + c) * 384 + a0 + tid] = sw + acc[p];
}

extern "C" void kernel_launch(void* const* d_in, const int* in_sizes, int n_in,
                              void* d_out, int out_size, void* d_ws, size_t ws_size,
                              hipStream_t stream) {
  (void)in_sizes; (void)n_in; (void)out_size; (void)ws_size;
  const float* seq  = (const float*)d_in[0];  // (768,768)
  const float* base = (const float*)d_in[1];  // (2,384,4,384)
  const float* Wp   = (const float*)d_in[2];  // (768,512)
  const float* Wpb  = (const float*)d_in[3];  // (512)
  const float* Ua   = (const float*)d_in[4];  // (768,512)
  const float* Uab  = (const float*)d_in[5];  // (512)
  const float* Wmid = (const float*)d_in[6];  // (768,128)
  const float* bmid = (const float*)d_in[7];  // (128)
  const float* wout = (const float*)d_in[8];  // (128)
  float* out = (float*)d_out;

  float* ws = (float*)d_ws;
  float* tanh_hp  = ws;                 // (3072,128) as (768,512)
  float* h_a      = ws + 393216;        // (768,512)
  float* tanh_ha  = ws + 786432;        // (768,512)
  float* tanh_ref = ws + 1179648;       // (768,512)
  float* tprd_s   = ws + 1572864;       // (3072,128), *C2
  float* tref_s   = ws + 1966080;       // (768,128),  *C2
  unsigned short* targ_s = (unsigned short*)(ws + 2064384);  // (3072,128) bf16, *C2

  dim3 blk(256);
  // G1a: tanh(seq@W_prd + b)
  gemm_bf16<<<dim3(8, 12, 1), blk, 0, stream>>>(
      seq, 768, 0, 0, Wp, 512, 0, 0, Wpb, 768, 512, 768,
      nullptr, nullptr, tanh_hp, 512, 0, 0, 1.f);
  // G1b: h_a = seq@U_arg + b  (raw + tanh)
  gemm_bf16<<<dim3(8, 12, 1), blk, 0, stream>>>(
      seq, 768, 0, 0, Ua, 512, 0, 0, Uab, 768, 512, 768,
      h_a, nullptr, tanh_ha, 512, 0, 0, 1.f);
  // G2: ref[b,p,c,:] = base_score[b,:,c,:] @ h_a[b,:,c,:] -> tanh, batched z=8
  gemm_bf16<<<dim3(2, 6, 8), blk, 0, stream>>>(
      base, 1536, 589824, 384, h_a, 512, 196608, 128, nullptr, 384, 128, 384,
      nullptr, nullptr, tanh_ref, 512, 196608, 128, 1.f);
  // G3: tprd_s = C2 * tanh(h_p) @ W1
  gemm_bf16<<<dim3(2, 48, 1), blk, 0, stream>>>(
      tanh_hp, 128, 0, 0, Wmid, 128, 0, 0, nullptr, 3072, 128, 128,
      tprd_s, nullptr, nullptr, 128, 0, 0, C2);
  // G4: targ_s = bf16(C2 * tanh(h_a) @ W2)
  gemm_bf16<<<dim3(2, 48, 1), blk, 0, stream>>>(
      tanh_ha, 128, 0, 0, Wmid + 16384, 128, 0, 0, nullptr, 3072, 128, 128,
      nullptr, targ_s, nullptr, 128, 0, 0, C2);
  // G5: tref_s = C2 * tanh(ref) @ W3
  gemm_bf16<<<dim3(2, 12, 1), blk, 0, stream>>>(
      tanh_ref, 512, 0, 0, Wmid + 32768, 128, 0, 0, nullptr, 768, 128, 512,
      tref_s, nullptr, nullptr, 128, 0, 0, C2);
  // Phase 2: the 151M-element tanh-dot
  phase2<<<dim3(48, 3, 8), dim3(128), 0, stream>>>(
      tprd_s, targ_s, tref_s, bmid, wout, out);
}

// Round 2
// 156.473 us; speedup vs baseline: 1.4028x; 1.4028x over previous
//
#include <hip/hip_runtime.h>
#include <hip/hip_bf16.h>

// RefinementLayer2: B=2,S=384,C=4,H=128,D=768
// ws layout (floats):
//   0        tanh_hp   (393216)  = tanh(seq@Wp+b)      as (3072,128)/(768,512)
//   393216   tanh_ha   (393216)  = tanh(seq@Ua+b)
//   786432   tanh_ref  (393216)  = tanh(ref)           (768,512)
//   1179648  h_a       (393216)  = seq@Ua+b            (768,512)
//   1572864  tprd_s    (393216)  = C2*tanh(h_p)@W1     (3072,128)
//   1966080  tref_s    (98304)   = C2*tanh(ref)@W3     (768,128)
//   2064384  targ_s    (196608 floats as bf16 shorts) = bf16(C2*tanh(h_a)@W2)
// total 2260992 floats = 9.04 MB

#define C2 2.885390081777927f  // 2/ln(2): exp2(C2*x) = e^(2x)

typedef __attribute__((ext_vector_type(8))) __bf16 bf16x8;
typedef __attribute__((ext_vector_type(8))) unsigned short ushort8;
typedef __attribute__((ext_vector_type(4))) float float4v;
typedef __attribute__((ext_vector_type(2))) float float2v;

__device__ __forceinline__ unsigned short f2bf(float f) {
  unsigned int u = __float_as_uint(f);
  u += 0x7fffu + ((u >> 16) & 1u);   // round-nearest-even
  return (unsigned short)(u >> 16);
}

__device__ __forceinline__ float fast_tanh(float x) {
  // tanh(x) = 1 - 2/(1+e^(2x)); inf-safe at both ends.
  float e = __builtin_amdgcn_exp2f(C2 * x);
  return 1.0f - 2.0f * __builtin_amdgcn_rcpf(1.0f + e);
}

// ---------------------------------------------------------------------------
// Generic fp32-in bf16-MFMA GEMM.  C = A(MxK) * B(KxN) + bias.
// 64x64 block tile, BK=32, 256 threads (4 waves, each 32x32 = 2x2 MFMA).
// Register double-buffer: next k-tile's global loads are issued before the
// MFMA section so HBM latency overlaps compute (grids here are ~1 block/CU).
// Batch via z: off = (z>>2)*Sb + (z&3)*Sc.  If B1 != null and z==1, B/bias
// switch to B1/bias1 (fused dual-weight launch).
// Per-z output enables: write outF/outB/outT iff bit z of fmask/bmask/tmask.
// ---------------------------------------------------------------------------
__global__ __launch_bounds__(256) void gemm_bf16(
    const float* __restrict__ A, int lda, long aSb, long aSc,
    const float* __restrict__ B0, int ldb, long bSb, long bSc,
    const float* __restrict__ B1,
    const float* __restrict__ bias0, const float* __restrict__ bias1,
    int M, int N, int K,
    float* __restrict__ outF, unsigned short* __restrict__ outB,
    float* __restrict__ outT, int ldc, long cSb, long cSc, float scale,
    int fmask, int bmask, int tmask)
{
  __shared__ unsigned short Alds[64 * 40];  // [m][k], pad 32->40
  __shared__ unsigned short Blds[64 * 40];  // [n][k] transposed, padded

  const int tid = threadIdx.x;
  const int z = blockIdx.z;
  const float* B = (z == 1 && B1) ? B1 : B0;
  const float* bias = (z == 1 && B1) ? bias1 : bias0;
  const long aoff = (long)(z >> 2) * aSb + (long)(z & 3) * aSc;
  const long boff = (long)(z >> 2) * bSb + (long)(z & 3) * bSc;
  const long coff = (long)(z >> 2) * cSb + (long)(z & 3) * cSc;
  const int bn0 = blockIdx.x * 64;
  const int bm0 = blockIdx.y * 64;
  const int wid = tid >> 6, lane = tid & 63;
  const int wm0 = (wid >> 1) * 32, wn0 = (wid & 1) * 32;
  const int col16 = lane & 15, quad = lane >> 4;

  float4v acc[2][2];
#pragma unroll
  for (int i = 0; i < 2; ++i)
#pragma unroll
    for (int j = 0; j < 2; ++j) acc[i][j] = (float4v)(0.f);

  const int ar = tid >> 2, ac = (tid & 3) * 8;       // A stage map
  const int bk = tid >> 3, bn = (tid & 7) * 8;       // B stage map

  const float* Abase = A + aoff + (size_t)(bm0 + ar) * lda + ac;
  const float* Bbase = B + boff + (size_t)bk * ldb + bn0 + bn;

  // initial prefetch (k0 = 0)
  float4 a0 = ((const float4*)Abase)[0], a1 = ((const float4*)Abase)[1];
  float4 b0 = ((const float4*)Bbase)[0], b1 = ((const float4*)Bbase)[1];

  for (int k0 = 0; k0 < K; k0 += 32) {
    __syncthreads();
    {  // write staged regs -> LDS (fp32 -> bf16)
      ushort8 o;
      o[0] = f2bf(a0.x); o[1] = f2bf(a0.y); o[2] = f2bf(a0.z); o[3] = f2bf(a0.w);
      o[4] = f2bf(a1.x); o[5] = f2bf(a1.y); o[6] = f2bf(a1.z); o[7] = f2bf(a1.w);
      *(ushort8*)&Alds[ar * 40 + ac] = o;
      float vv[8] = {b0.x, b0.y, b0.z, b0.w, b1.x, b1.y, b1.z, b1.w};
#pragma unroll
      for (int j = 0; j < 8; ++j) Blds[(bn + j) * 40 + bk] = f2bf(vv[j]);
    }
    __syncthreads();

    if (k0 + 32 < K) {  // prefetch next tile; in flight during MFMA below
      const float4* An = (const float4*)(Abase + k0 + 32);
      const float4* Bn = (const float4*)(Bbase + (size_t)(k0 + 32) * ldb);
      a0 = An[0]; a1 = An[1];
      b0 = Bn[0]; b1 = Bn[1];
    }

    bf16x8 afrag[2], bfrag[2];
#pragma unroll
    for (int i = 0; i < 2; ++i)
      afrag[i] = __builtin_bit_cast(bf16x8,
          *(const ushort8*)&Alds[(wm0 + i * 16 + col16) * 40 + quad * 8]);
#pragma unroll
    for (int j = 0; j < 2; ++j)
      bfrag[j] = __builtin_bit_cast(bf16x8,
          *(const ushort8*)&Blds[(wn0 + j * 16 + col16) * 40 + quad * 8]);
#pragma unroll
    for (int i = 0; i < 2; ++i)
#pragma unroll
      for (int j = 0; j < 2; ++j)
        acc[i][j] = __builtin_amdgcn_mfma_f32_16x16x32_bf16(
            afrag[i], bfrag[j], acc[i][j], 0, 0, 0);
  }

  const bool wF = outF && ((fmask >> z) & 1);
  const bool wB = outB && ((bmask >> z) & 1);
  const bool wT = outT && ((tmask >> z) & 1);

  // epilogue: C/D layout col=lane&15, row=quad*4+reg
#pragma unroll
  for (int j = 0; j < 2; ++j) {
    const int gcol = bn0 + wn0 + j * 16 + col16;
    const float bv = bias ? bias[gcol] : 0.f;
#pragma unroll
    for (int i = 0; i < 2; ++i) {
#pragma unroll
      for (int r = 0; r < 4; ++r) {
        const int grow = bm0 + wm0 + i * 16 + quad * 4 + r;
        const float x = acc[i][j][r] + bv;
        const size_t cidx = (size_t)grow * ldc + gcol + coff;
        if (wF) outF[cidx] = scale * x;
        if (wB) outB[cidx] = f2bf(scale * x);
        if (wT) outT[cidx] = fast_tanh(x);
      }
    }
  }
}

// ---------------------------------------------------------------------------
// Phase 2: out[b,p,c,a] = sum_k w[k] * tanh(t_prd[b,p,c,k] + t_arg[b,a,c,k]
//                                          + t_ref[b,p,k] + b_mid[k])
// t_* pre-scaled by C2.  tanh = 1 - 2*rcp(1 + e_f*e_g) with
// e_f = exp2(tprd+tref+C2*bmid) precomputed in LDS (Es, shared over all a),
// e_g = exp2(t_arg) computed per thread (2 exps amortized over 8 p).
// k split into two 64-wide passes through one half-size Gs buffer ->
// LDS ~22 KB -> 7 blocks/CU -> all 1152 blocks co-resident, no tail.
// ---------------------------------------------------------------------------
__global__ __launch_bounds__(128) void phase2(
    const float* __restrict__ tprd, const unsigned short* __restrict__ targ,
    const float* __restrict__ tref, const float* __restrict__ bmid,
    const float* __restrict__ wout, float* __restrict__ out)
{
  __shared__ unsigned int Gs[128 * 34];  // [a][k-pair], stride 34 (8B-aligned rows)
  __shared__ float Es[8 * 128];          // exp2(f[p][k])
  __shared__ float Ws[128];              // -2*w[k]

  const int tid = threadIdx.x;
  const int p0 = blockIdx.x * 8, a0 = blockIdx.y * 128;
  const int b = blockIdx.z >> 2, c = blockIdx.z & 3;

  if (tid < 32) {
    float4 w = ((const float4*)wout)[tid];
    Ws[tid * 4 + 0] = -2.f * w.x; Ws[tid * 4 + 1] = -2.f * w.y;
    Ws[tid * 4 + 2] = -2.f * w.z; Ws[tid * 4 + 3] = -2.f * w.w;
  }
#pragma unroll
  for (int it = 0; it < 8; ++it) {  // Es[p][k] = exp2(tprd+tref+C2*bmid)
    int idx = it * 128 + tid;
    int p = idx >> 7, k = idx & 127;
    int row = b * 384 + p0 + p;
    float f = tprd[(size_t)(row * 4 + c) * 128 + k] +
              tref[(size_t)row * 128 + k] + C2 * bmid[k];
    Es[idx] = __builtin_amdgcn_exp2f(f);
  }
  float sw = 0.f;  // Sum(w) via uniform loads
  for (int k4 = 0; k4 < 32; ++k4) {
    float4 w = ((const float4*)wout)[k4];
    sw += w.x + w.y + w.z + w.w;
  }

  float2v accA[8], accB[8];
#pragma unroll
  for (int p = 0; p < 8; ++p) { accA[p] = (float2v)(0.f); accB[p] = (float2v)(0.f); }

  const unsigned int* gsrc = (const unsigned int*)targ;
  const size_t grow_base = (size_t)((b * 384 + a0) * 4 + c) * 64;

  for (int h = 0; h < 2; ++h) {
    __syncthreads();  // h=0: Es/Ws ready; h=1: previous Gs readers done
#pragma unroll 8
    for (int it = 0; it < 32; ++it) {  // stage Gs: 128 rows x 32 uints
      int idx = it * 128 + tid;
      int r = idx >> 5, col = idx & 31;
      Gs[r * 34 + col] = gsrc[grow_base + (size_t)r * 256 + h * 32 + col];
    }
    __syncthreads();

    const unsigned int* g = &Gs[tid * 34];
    const int kb = h * 64;
    for (int j = 0; j < 16; ++j) {  // 4 k-values per j
      uint2 gp = *(const uint2*)(g + j * 2);
      float eg0 = __builtin_amdgcn_exp2f(__uint_as_float(gp.x << 16));
      float eg1 = __builtin_amdgcn_exp2f(__uint_as_float(gp.x & 0xffff0000u));
      float eg2 = __builtin_amdgcn_exp2f(__uint_as_float(gp.y << 16));
      float eg3 = __builtin_amdgcn_exp2f(__uint_as_float(gp.y & 0xffff0000u));
      float2v w01 = *(const float2v*)&Ws[kb + j * 4];
      float2v w23 = *(const float2v*)&Ws[kb + j * 4 + 2];
#pragma unroll
      for (int p = 0; p < 8; ++p) {
        float4 ef = *(const float4*)&Es[p * 128 + kb + j * 4];
        float2v e01 = {ef.x * eg0, ef.y * eg1};
        float2v e23 = {ef.z * eg2, ef.w * eg3};
        float2v d01 = e01 + 1.f;
        float2v d23 = e23 + 1.f;
        float2v r01 = {__builtin_amdgcn_rcpf(d01.x), __builtin_amdgcn_rcpf(d01.y)};
        float2v r23 = {__builtin_amdgcn_rcpf(d23.x), __builtin_amdgcn_rcpf(d23.y)};
        accA[p] += w01 * r01;
        accB[p] += w23 * r23;
      }
    }
  }

  const size_t ob = (size_t)((b * 384 + p0) * 4 + c) * 384 + a0 + tid;
#pragma unroll
  for (int p = 0; p < 8; ++p)
    out[ob + (size_t)p * 1536] = sw + accA[p].x + accA[p].y + accB[p].x + accB[p].y;
}

extern "C" void kernel_launch(void* const* d_in, const int* in_sizes, int n_in,
                              void* d_out, int out_size, void* d_ws, size_t ws_size,
                              hipStream_t stream) {
  (void)in_sizes; (void)n_in; (void)out_size; (void)ws_size;
  const float* seq  = (const float*)d_in[0];  // (768,768)
  const float* base = (const float*)d_in[1];  // (2,384,4,384)
  const float* Wp   = (const float*)d_in[2];  // (768,512)
  const float* Wpb  = (const float*)d_in[3];  // (512)
  const float* Ua   = (const float*)d_in[4];  // (768,512)
  const float* Uab  = (const float*)d_in[5];  // (512)
  const float* Wmid = (const float*)d_in[6];  // (768,128)
  const float* bmid = (const float*)d_in[7];  // (128)
  const float* wout = (const float*)d_in[8];  // (128)
  float* out = (float*)d_out;

  float* ws = (float*)d_ws;
  float* tanh_hp  = ws;                  // (768,512)
  float* tanh_ref = ws + 786432;         // (768,512)
  float* h_a      = ws + 1179648;        // (768,512)
  float* tprd_s   = ws + 1572864;        // (3072,128) *C2
  float* tref_s   = ws + 1966080;        // (768,128)  *C2
  unsigned short* targ_s = (unsigned short*)(ws + 2064384);  // (3072,128) bf16 *C2

  dim3 blk(256);
  // G1 fused (z=0: Wp -> tanh_hp; z=1: Ua -> h_a + tanh_ha at tanh_hp+393216)
  gemm_bf16<<<dim3(8, 12, 2), blk, 0, stream>>>(
      seq, 768, 0, 0, Wp, 512, 0, 0, Ua, Wpb, Uab, 768, 512, 768,
      /*outF base; only z=1 deref'd at +cSc = h_a*/ h_a - 393216, nullptr,
      /*outT*/ tanh_hp, 512, 0, 393216, 1.f, /*f*/0b10, 0, /*t*/0b11);
  // G2: tanh_ref[b,p,c,:] = tanh(base[b,:,c,:] @ h_a[b,:,c,:]), z=(b,c)
  gemm_bf16<<<dim3(2, 6, 8), blk, 0, stream>>>(
      base, 1536, 589824, 384, h_a, 512, 196608, 128, nullptr, nullptr, nullptr,
      384, 128, 384, nullptr, nullptr, tanh_ref, 512, 196608, 128, 1.f,
      0, 0, 0xFF);
  // G3+G4 fused: z=0: tprd_s = C2*tanh_hp@W1 (fp32); z=1: targ_s = bf16(C2*tanh_ha@W2)
  gemm_bf16<<<dim3(2, 48, 2), blk, 0, stream>>>(
      tanh_hp, 128, 0, 393216, Wmid, 128, 0, 16384, nullptr, nullptr, nullptr,
      3072, 128, 128, tprd_s, targ_s, nullptr, 128, 0, 0, C2,
      /*f*/0b01, /*b*/0b10, 0);
  // G5: tref_s = C2*tanh_ref@W3
  gemm_bf16<<<dim3(2, 12, 1), blk, 0, stream>>>(
      tanh_ref, 512, 0, 0, Wmid + 32768, 128, 0, 0, nullptr, nullptr, nullptr,
      768, 128, 512, tref_s, nullptr, nullptr, 128, 0, 0, C2, 1, 0, 0);
  // Phase 2
  phase2<<<dim3(48, 3, 8), dim3(128), 0, stream>>>(
      tprd_s, targ_s, tref_s, bmid, wout, out);
}

// Round 3
// 140.475 us; speedup vs baseline: 1.5625x; 1.1139x over previous
//
#include <hip/hip_runtime.h>
#include <hip/hip_bf16.h>

// RefinementLayer2: B=2,S=384,C=4,H=128,D=768
// ws layout (floats):
//   0        tanh_hp  (393216) = tanh(seq@Wp+b)   (768,512) [z=0 slice of pair]
//   393216   tanh_ha  (393216) = tanh(seq@Ua+b)
//   786432   h_a      (393216) = seq@Ua+b         (768,512)
//   1179648  tprd_s   (393216) = C2*tanh(h_p)@W1  (3072,128)
//   1572864  tref_s   (98304)  = C2*tanh(ref)@W3  (768,128)  [atomic-accumulated]
//   1671168  targ_s   (196608 floats as bf16)     (3072,128)

#define C2 2.885390081777927f  // 2/ln(2): exp2(C2*x) = e^(2x)

typedef __attribute__((ext_vector_type(8))) __bf16 bf16x8;
typedef __attribute__((ext_vector_type(8))) unsigned short ushort8;
typedef __attribute__((ext_vector_type(4))) float float4v;

__device__ __forceinline__ unsigned short f2bf(float f) {
  unsigned int u = __float_as_uint(f);
  u += 0x7fffu + ((u >> 16) & 1u);
  return (unsigned short)(u >> 16);
}

__device__ __forceinline__ float fast_tanh(float x) {
  float e = __builtin_amdgcn_exp2f(C2 * x);
  return 1.0f - 2.0f * __builtin_amdgcn_rcpf(1.0f + e);
}

// Shared 64x64-tile bf16-MFMA core, BK=32, 256 threads (4 waves, 32x32 each).
// Abase/Bbase pre-offset to the tile. Register double-buffer global prefetch.
__device__ __forceinline__ void gemm_core(
    const float* __restrict__ Abase, int lda,
    const float* __restrict__ Bbase, int ldb, int K,
    unsigned short* Alds, unsigned short* Blds,
    int ar, int ac, int bk, int bn,
    int wm0, int wn0, int col16, int quad, float4v acc[2][2])
{
  const float* Ap = Abase + (size_t)ar * lda + ac;
  const float* Bp = Bbase + (size_t)bk * ldb + bn;
  float4 a0 = ((const float4*)Ap)[0], a1 = ((const float4*)Ap)[1];
  float4 b0 = ((const float4*)Bp)[0], b1 = ((const float4*)Bp)[1];

  for (int k0 = 0; k0 < K; k0 += 32) {
    __syncthreads();
    {
      ushort8 o;
      o[0] = f2bf(a0.x); o[1] = f2bf(a0.y); o[2] = f2bf(a0.z); o[3] = f2bf(a0.w);
      o[4] = f2bf(a1.x); o[5] = f2bf(a1.y); o[6] = f2bf(a1.z); o[7] = f2bf(a1.w);
      *(ushort8*)&Alds[ar * 40 + ac] = o;
      float vv[8] = {b0.x, b0.y, b0.z, b0.w, b1.x, b1.y, b1.z, b1.w};
#pragma unroll
      for (int j = 0; j < 8; ++j) Blds[(bn + j) * 40 + bk] = f2bf(vv[j]);
    }
    __syncthreads();
    if (k0 + 32 < K) {
      const float4* An = (const float4*)(Ap + k0 + 32);
      const float4* Bn = (const float4*)(Bp + (size_t)(k0 + 32) * ldb);
      a0 = An[0]; a1 = An[1]; b0 = Bn[0]; b1 = Bn[1];
    }
    bf16x8 afrag[2], bfrag[2];
#pragma unroll
    for (int i = 0; i < 2; ++i)
      afrag[i] = __builtin_bit_cast(bf16x8,
          *(const ushort8*)&Alds[(wm0 + i * 16 + col16) * 40 + quad * 8]);
#pragma unroll
    for (int j = 0; j < 2; ++j)
      bfrag[j] = __builtin_bit_cast(bf16x8,
          *(const ushort8*)&Blds[(wn0 + j * 16 + col16) * 40 + quad * 8]);
#pragma unroll
    for (int i = 0; i < 2; ++i)
#pragma unroll
      for (int j = 0; j < 2; ++j)
        acc[i][j] = __builtin_amdgcn_mfma_f32_16x16x32_bf16(
            afrag[i], bfrag[j], acc[i][j], 0, 0, 0);
  }
}

// D1: z=0: tanh(seq@Wp+b) -> tanh_out; z=1: seq@Ua+b -> h_a (+tanh at +393216);
//     z=2: zero tref (96 blocks x 256 thr x 1 float4 = 98304 floats).
__global__ __launch_bounds__(256) void g1_dual(
    const float* __restrict__ seq, const float* __restrict__ Wp,
    const float* __restrict__ Ua, const float* __restrict__ Wpb,
    const float* __restrict__ Uab, float* __restrict__ tanh_out,
    float* __restrict__ h_a, float* __restrict__ tref_clear)
{
  const int z = blockIdx.z;
  if (z == 2) {
    int idx = ((blockIdx.y * 8 + blockIdx.x) * 256 + threadIdx.x) * 4;
    *(float4*)&tref_clear[idx] = float4{0.f, 0.f, 0.f, 0.f};
    return;
  }
  __shared__ unsigned short Alds[64 * 40];
  __shared__ unsigned short Blds[64 * 40];
  const int tid = threadIdx.x;
  const int bn0 = blockIdx.x * 64, bm0 = blockIdx.y * 64;
  const int wid = tid >> 6, lane = tid & 63;
  const int wm0 = (wid >> 1) * 32, wn0 = (wid & 1) * 32;
  const int col16 = lane & 15, quad = lane >> 4;
  const float* B = z ? Ua : Wp;
  const float* bias = z ? Uab : Wpb;

  float4v acc[2][2];
#pragma unroll
  for (int i = 0; i < 2; ++i)
#pragma unroll
    for (int j = 0; j < 2; ++j) acc[i][j] = (float4v)(0.f);

  gemm_core(seq + (size_t)bm0 * 768, 768, B + bn0, 512, 768,
            Alds, Blds, tid >> 2, (tid & 3) * 8, tid >> 3, (tid & 7) * 8,
            wm0, wn0, col16, quad, acc);

  float* tout = tanh_out + (size_t)z * 393216;
#pragma unroll
  for (int j = 0; j < 2; ++j) {
    const int gcol = bn0 + wn0 + j * 16 + col16;
    const float bv = bias[gcol];
#pragma unroll
    for (int i = 0; i < 2; ++i)
#pragma unroll
      for (int r = 0; r < 4; ++r) {
        const int grow = bm0 + wm0 + i * 16 + quad * 4 + r;
        const float x = acc[i][j][r] + bv;
        const size_t cidx = (size_t)grow * 512 + gcol;
        tout[cidx] = fast_tanh(x);
        if (z == 1) h_a[cidx] = x;
      }
  }
}

// D2: job table, 288 blocks.
//  bid<96 : G2' — ref tile = base[b,:,c,:]@h_a[b,:,c,:] (64x64, K=384), then
//           tail MFMA: tref[rows,0:128] += C2*tanh(tile)@W3[c*128+x*64 .. +64]
//           via fp32 atomicAdd.
//  bid>=96: G3/G4 — tanh_h{p,a}@W{1,2} (M=3072,N=128,K=128); z0 -> tprd fp32,
//           z1 -> targ bf16, both *C2.
__global__ __launch_bounds__(256) void fused_mid(
    const float* __restrict__ base, const float* __restrict__ h_a,
    const float* __restrict__ tanh_h, const float* __restrict__ Wmid,
    float* __restrict__ tprd_s, unsigned short* __restrict__ targ_s,
    float* __restrict__ tref_s)
{
  __shared__ unsigned short Alds[64 * 40];
  __shared__ unsigned short Blds[64 * 40];
  __shared__ unsigned short TA[64 * 72];    // tanh tile [m][k]
  __shared__ unsigned short TB[128 * 72];   // W3 slice  [n][k]

  const int tid = threadIdx.x;
  const int bid = blockIdx.x;
  const int wid = tid >> 6, lane = tid & 63;
  const int wm0 = (wid >> 1) * 32, wn0 = (wid & 1) * 32;
  const int col16 = lane & 15, quad = lane >> 4;
  const int ar = tid >> 2, ac = (tid & 3) * 8;
  const int bk = tid >> 3, bn = (tid & 7) * 8;

  float4v acc[2][2];
#pragma unroll
  for (int i = 0; i < 2; ++i)
#pragma unroll
    for (int j = 0; j < 2; ++j) acc[i][j] = (float4v)(0.f);

  if (bid < 96) {
    const int z = bid / 12, rem = bid % 12;
    const int b = z >> 2, c = z & 3;
    const int y = rem >> 1, x = rem & 1;
    const float* A = base + (size_t)b * 589824 + c * 384 + (size_t)(y * 64) * 1536;
    const float* Bm = h_a + (size_t)b * 196608 + c * 128 + x * 64;
    gemm_core(A, 1536, Bm, 512, 384, Alds, Blds, ar, ac, bk, bn,
              wm0, wn0, col16, quad, acc);

    // tanh tile -> TA [m][k] bf16
#pragma unroll
    for (int j = 0; j < 2; ++j)
#pragma unroll
      for (int i = 0; i < 2; ++i)
#pragma unroll
        for (int r = 0; r < 4; ++r)
          TA[(wm0 + i * 16 + quad * 4 + r) * 72 + wn0 + j * 16 + col16] =
              f2bf(fast_tanh(acc[i][j][r]));
    // stage W3 slice: rows kglob = c*128+x*64+(0..63), 128 cols -> TB [n][k]
    {
      const float* W3p = Wmid + 32768 + (size_t)(c * 128 + x * 64) * 128;
      const int kr = tid >> 2, nb = (tid & 3) * 32;
#pragma unroll
      for (int q = 0; q < 8; ++q) {
        float4 v = *(const float4*)(W3p + (size_t)kr * 128 + nb + q * 4);
        TB[(nb + q * 4 + 0) * 72 + kr] = f2bf(v.x);
        TB[(nb + q * 4 + 1) * 72 + kr] = f2bf(v.y);
        TB[(nb + q * 4 + 2) * 72 + kr] = f2bf(v.z);
        TB[(nb + q * 4 + 3) * 72 + kr] = f2bf(v.w);
      }
    }
    __syncthreads();

    // tail MFMA: M=64 (mh), N=128 (nh), K=64. wave: mh=wid&1, nh=wid>>1.
    const int mh = wid & 1, nh = wid >> 1;
    float4v acc2[2][4];
#pragma unroll
    for (int i = 0; i < 2; ++i)
#pragma unroll
      for (int j = 0; j < 4; ++j) acc2[i][j] = (float4v)(0.f);
#pragma unroll
    for (int ks = 0; ks < 2; ++ks) {
      bf16x8 af[2], bf[4];
#pragma unroll
      for (int i = 0; i < 2; ++i)
        af[i] = __builtin_bit_cast(bf16x8,
            *(const ushort8*)&TA[(mh * 32 + i * 16 + col16) * 72 + ks * 32 + quad * 8]);
#pragma unroll
      for (int j = 0; j < 4; ++j)
        bf[j] = __builtin_bit_cast(bf16x8,
            *(const ushort8*)&TB[(nh * 64 + j * 16 + col16) * 72 + ks * 32 + quad * 8]);
#pragma unroll
      for (int i = 0; i < 2; ++i)
#pragma unroll
        for (int j = 0; j < 4; ++j)
          acc2[i][j] = __builtin_amdgcn_mfma_f32_16x16x32_bf16(
              af[i], bf[j], acc2[i][j], 0, 0, 0);
    }
#pragma unroll
    for (int j = 0; j < 4; ++j) {
      const int gcol = nh * 64 + j * 16 + col16;
#pragma unroll
      for (int i = 0; i < 2; ++i)
#pragma unroll
        for (int r = 0; r < 4; ++r) {
          const int grow = b * 384 + y * 64 + mh * 32 + i * 16 + quad * 4 + r;
          atomicAdd(&tref_s[(size_t)grow * 128 + gcol], C2 * acc2[i][j][r]);
        }
    }
  } else {
    const int idx = bid - 96;
    const int x = idx & 1, y = (idx >> 1) % 48, z = idx / 96;
    const float* A = tanh_h + (size_t)z * 393216 + (size_t)(y * 64) * 128;
    const float* Bm = Wmid + z * 16384 + x * 64;
    gemm_core(A, 128, Bm, 128, 128, Alds, Blds, ar, ac, bk, bn,
              wm0, wn0, col16, quad, acc);
#pragma unroll
    for (int j = 0; j < 2; ++j) {
      const int gcol = x * 64 + wn0 + j * 16 + col16;
#pragma unroll
      for (int i = 0; i < 2; ++i)
#pragma unroll
        for (int r = 0; r < 4; ++r) {
          const int grow = y * 64 + wm0 + i * 16 + quad * 4 + r;
          const float v = C2 * acc[i][j][r];
          const size_t cidx = (size_t)grow * 128 + gcol;
          if (z == 0) tprd_s[cidx] = v;
          else        targ_s[cidx] = f2bf(v);
        }
    }
  }
}

// D3: out[b,p,c,a] = sum_k w_k * tanh(tprd+targ+tref+bmid).
// tanh = 1 - 2*rcp(1+ef*eg); paired: w0/d0+w1/d1 = (w0*d1+w1*d0)*rcp(d0*d1).
__global__ __launch_bounds__(128) void phase2(
    const float* __restrict__ tprd, const unsigned short* __restrict__ targ,
    const float* __restrict__ tref, const float* __restrict__ bmid,
    const float* __restrict__ wout, float* __restrict__ out)
{
  __shared__ unsigned int Gs[128 * 34];
  __shared__ float Es[8 * 128];
  __shared__ float Ws[128];

  const int tid = threadIdx.x;
  const int p0 = blockIdx.x * 8, a0 = blockIdx.y * 128;
  const int b = blockIdx.z >> 2, c = blockIdx.z & 3;

  if (tid < 32) {
    float4 w = ((const float4*)wout)[tid];
    Ws[tid * 4 + 0] = -2.f * w.x; Ws[tid * 4 + 1] = -2.f * w.y;
    Ws[tid * 4 + 2] = -2.f * w.z; Ws[tid * 4 + 3] = -2.f * w.w;
  }
#pragma unroll
  for (int it = 0; it < 8; ++it) {
    int idx = it * 128 + tid;
    int p = idx >> 7, k = idx & 127;
    int row = b * 384 + p0 + p;
    float f = tprd[(size_t)(row * 4 + c) * 128 + k] +
              tref[(size_t)row * 128 + k] + C2 * bmid[k];
    Es[idx] = __builtin_amdgcn_exp2f(f);
  }
  float sw = 0.f;
  for (int k4 = 0; k4 < 32; ++k4) {
    float4 w = ((const float4*)wout)[k4];
    sw += w.x + w.y + w.z + w.w;
  }

  float acc01[8], acc23[8];
#pragma unroll
  for (int p = 0; p < 8; ++p) { acc01[p] = 0.f; acc23[p] = 0.f; }

  const unsigned int* gsrc = (const unsigned int*)targ;
  const size_t grow_base = (size_t)((b * 384 + a0) * 4 + c) * 64;

  for (int h = 0; h < 2; ++h) {
    __syncthreads();
#pragma unroll 8
    for (int it = 0; it < 32; ++it) {
      int idx = it * 128 + tid;
      int r = idx >> 5, col = idx & 31;
      Gs[r * 34 + col] = gsrc[grow_base + (size_t)r * 256 + h * 32 + col];
    }
    __syncthreads();

    const unsigned int* g = &Gs[tid * 34];
    const int kb = h * 64;
#pragma unroll 2
    for (int j = 0; j < 16; ++j) {
      uint2 gp = *(const uint2*)(g + j * 2);
      float eg0 = __builtin_amdgcn_exp2f(__uint_as_float(gp.x << 16));
      float eg1 = __builtin_amdgcn_exp2f(__uint_as_float(gp.x & 0xffff0000u));
      float eg2 = __builtin_amdgcn_exp2f(__uint_as_float(gp.y << 16));
      float eg3 = __builtin_amdgcn_exp2f(__uint_as_float(gp.y & 0xffff0000u));
      float4 wq = *(const float4*)&Ws[kb + j * 4];
#pragma unroll
      for (int p = 0; p < 8; ++p) {
        float4 ef = *(const float4*)&Es[p * 128 + kb + j * 4];
        float d0 = fmaf(ef.x, eg0, 1.f);
        float d1 = fmaf(ef.y, eg1, 1.f);
        float d2 = fmaf(ef.z, eg2, 1.f);
        float d3 = fmaf(ef.w, eg3, 1.f);
        float r01 = __builtin_amdgcn_rcpf(d0 * d1);
        float r23 = __builtin_amdgcn_rcpf(d2 * d3);
        float n01 = fmaf(wq.y, d0, wq.x * d1);
        float n23 = fmaf(wq.w, d2, wq.z * d3);
        acc01[p] = fmaf(n01, r01, acc01[p]);
        acc23[p] = fmaf(n23, r23, acc23[p]);
      }
    }
  }

  const size_t ob = (size_t)((b * 384 + p0) * 4 + c) * 384 + a0 + tid;
#pragma unroll
  for (int p = 0; p < 8; ++p)
    out[ob + (size_t)p * 1536] = sw + acc01[p] + acc23[p];
}

extern "C" void kernel_launch(void* const* d_in, const int* in_sizes, int n_in,
                              void* d_out, int out_size, void* d_ws, size_t ws_size,
                              hipStream_t stream) {
  (void)in_sizes; (void)n_in; (void)out_size; (void)ws_size;
  const float* seq  = (const float*)d_in[0];
  const float* base = (const float*)d_in[1];
  const float* Wp   = (const float*)d_in[2];
  const float* Wpb  = (const float*)d_in[3];
  const float* Ua   = (const float*)d_in[4];
  const float* Uab  = (const float*)d_in[5];
  const float* Wmid = (const float*)d_in[6];
  const float* bmid = (const float*)d_in[7];
  const float* wout = (const float*)d_in[8];
  float* out = (float*)d_out;

  float* ws = (float*)d_ws;
  float* tanh_hp = ws;                    // (768,512) x2 (z=0 hp, z=1 ha)
  float* h_a     = ws + 786432;           // (768,512)
  float* tprd_s  = ws + 1179648;          // (3072,128) *C2
  float* tref_s  = ws + 1572864;          // (768,128)  *C2, atomic
  unsigned short* targ_s = (unsigned short*)(ws + 1671168);  // (3072,128) bf16 *C2

  g1_dual<<<dim3(8, 12, 3), dim3(256), 0, stream>>>(
      seq, Wp, Ua, Wpb, Uab, tanh_hp, h_a, tref_s);
  fused_mid<<<dim3(288), dim3(256), 0, stream>>>(
      base, h_a, tanh_hp, Wmid, tprd_s, targ_s, tref_s);
  phase2<<<dim3(48, 3, 8), dim3(128), 0, stream>>>(
      tprd_s, targ_s, tref_s, bmid, wout, out);
}